// Round 9
// baseline (551.324 us; speedup 1.0000x reference)
//
#include <hip/hip_runtime.h>
#include <hip/hip_bf16.h>

// ---------------------------------------------------------------------------
// TransformerMoEDecoderLayer: SA -> add+LN -> CA -> add+LN -> MoE top2 -> add+LN
// T=S=1024, B=4, D=1024, H=16, HD=64, F=4096, E=8, N=4096, CAP=1024
// Round 9: k_gemm8p ks-split ds_read scheduling (ks0 pre-barrier, ks1 under
//          MFMA cluster) + base-pointer staging (-12 VGPR). Rest = round 8.
// ---------------------------------------------------------------------------

typedef __bf16 bf16;
typedef __bf16 bf16x2 __attribute__((ext_vector_type(2)));
typedef __bf16 bf16x4 __attribute__((ext_vector_type(4)));
typedef __bf16 bf16x8 __attribute__((ext_vector_type(8)));
typedef float  f32x4  __attribute__((ext_vector_type(4)));

static_assert(sizeof(bf16) == 2, "bf16 size");

#define CAP_ 1024

#define GLOAD16(g, l)                                                  \
  __builtin_amdgcn_global_load_lds(                                    \
      (const __attribute__((address_space(1))) unsigned int*)(g),      \
      (__attribute__((address_space(3))) unsigned int*)(l), 16, 0, 0)

#define BAR() do { asm volatile("" ::: "memory"); __builtin_amdgcn_s_barrier(); asm volatile("" ::: "memory"); } while (0)

// ---------------- workspace layout (bytes) ----------------
static const long OFF_WSAIN  = 0L;                         // bf16 [3072][1024]
static const long OFF_WSAOUT = 6291456L;                   // bf16 [1024][1024]
static const long OFF_WCAIN  = 8388608L;                   // bf16 [3072][1024]
static const long OFF_WCAOUT = 14680064L;                  // bf16 [1024][1024]
static const long OFF_BTGT   = 16777216L;                  // bf16 [4096][1024] (later x1b)
static const long OFF_BMEM   = 25165824L;                  // bf16 [4096][1024]
static const long OFF_QKV    = 33554432L;                  // 3 slices bf16 [4][1024][1024]; phase3: expert buf + eo partial1
static const long OFF_QS     = OFF_QKV;
static const long OFF_KS     = OFF_QKV + 8388608L;
static const long OFF_VS     = OFF_QKV + 16777216L;
static const long OFF_EO1    = 33554432L;                  // bf16 [8][1024][1024] partial1
static const long OFF_VT     = 58720256L;                  // bf16 [64][64][1024]
static const long OFF_AO     = 67108864L;                  // bf16 [4096][1024]
static const long OFF_PROJ   = 75497472L;                  // f32 [4096][1024]; phase3: eo partial0 bf16
static const long OFF_X1     = 92274688L;                  // f32 [4096][1024]
static const long OFF_X2     = 109051904L;                 // f32 [4096][1024]
static const long OFF_SCORES = 125829120L;                 // phase3: w1t/w2t 64MB
static const long OFF_H      = OFF_SCORES + 67108864L;     // bf16 [8][1024][4096]
static const long OFF_GATE   = 260046848L;
static const long OFF_E1   = OFF_GATE;
static const long OFF_E2   = OFF_GATE + 16384L;
static const long OFF_G1   = OFF_GATE + 32768L;
static const long OFF_G2   = OFF_GATE + 49152L;
static const long OFF_D1   = OFF_GATE + 65536L;
static const long OFF_D2   = OFF_GATE + 81920L;
static const long OFF_S1   = OFF_GATE + 98304L;
static const long OFF_S2   = OFF_GATE + 114688L;

// T1: bijective XCD chunk swizzle (m204).
__device__ __forceinline__ int xcd_swz(int bid, int nwg) {
  int q = nwg >> 3, r = nwg & 7;
  int xcd = bid & 7, idx = bid >> 3;
  return (xcd < r ? xcd * (q + 1) : r * (q + 1) + (xcd - r) * q) + idx;
}

// ---------------- fused fp32 -> bf16 conversions ----------------
__global__ __launch_bounds__(256) void k_cvt6(
    const float* __restrict__ s0, const float* __restrict__ s1,
    const float* __restrict__ s2, const float* __restrict__ s3,
    const float* __restrict__ s4, const float* __restrict__ s5,
    bf16* __restrict__ d0, bf16* __restrict__ d1, bf16* __restrict__ d2,
    bf16* __restrict__ d3, bf16* __restrict__ d4, bf16* __restrict__ d5) {
  long b = blockIdx.x;
  const float* s; bf16* d; long off;
  if (b < 3072)       { s = s0; d = d0; off = b; }
  else if (b < 4096)  { s = s1; d = d1; off = b - 3072; }
  else if (b < 7168)  { s = s2; d = d2; off = b - 4096; }
  else if (b < 8192)  { s = s3; d = d3; off = b - 7168; }
  else if (b < 12288) { s = s4; d = d4; off = b - 8192; }
  else                { s = s5; d = d5; off = b - 12288; }
  long i = off * 256 + threadIdx.x;
  float4 v = ((const float4*)s)[i];
  bf16x4 o = {(bf16)v.x, (bf16)v.y, (bf16)v.z, (bf16)v.w};
  ((bf16x4*)d)[i] = o;
}

// ---------------- transpose fp32 [z][R][C] -> bf16 [z][C][R] ----------------
__global__ __launch_bounds__(256) void k_transpose_f32_bf16(const float* __restrict__ in,
                                                            bf16* __restrict__ out, int R, int C) {
  __shared__ float t[64][66];
  int z = blockIdx.z;
  long r0 = (long)blockIdx.y * 64, c0 = (long)blockIdx.x * 64;
  const float* ib = in + (long)z * R * C;
  bf16* ob = out + (long)z * R * C;
  int tid = threadIdx.x;
  int x = tid & 15, y = tid >> 4;
  #pragma unroll
  for (int j = 0; j < 4; j++) {
    int sr = y + j * 16;
    float4 v = *(const float4*)&ib[(r0 + sr) * C + c0 + x * 4];
    t[sr][x * 4 + 0] = v.x; t[sr][x * 4 + 1] = v.y;
    t[sr][x * 4 + 2] = v.z; t[sr][x * 4 + 3] = v.w;
  }
  __syncthreads();
  int xs = tid & 7, jj = tid >> 3;   // 8 x 32
  #pragma unroll
  for (int p = 0; p < 2; p++) {
    int c = jj + p * 32;
    bf16x8 o;
    #pragma unroll
    for (int k = 0; k < 8; k++) o[k] = (bf16)t[xs * 8 + k][c];
    *(bf16x8*)&ob[(c0 + c) * R + r0 + xs * 8] = o;
  }
}

// ---------------- extract V^T per head: [4][1024][1024] -> vt[bh][64][1024] --
__global__ __launch_bounds__(256) void k_extract_vt(const bf16* __restrict__ in,
                                                    bf16* __restrict__ out) {
  __shared__ bf16 t[64][68];
  const int bh = blockIdx.y;
  const long r0 = (long)blockIdx.x * 64;
  const int b = bh >> 4, h = bh & 15;
  const bf16* ib = in + (long)b * 1048576 + h * 64;
  bf16* ob = out + (long)bh * 65536;
  int tid = threadIdx.x;
  int x = tid & 15, y = tid >> 4;
  #pragma unroll
  for (int j = 0; j < 4; j++) {
    int sr = y + j * 16;
    *(bf16x4*)&t[sr][x * 4] = *(const bf16x4*)&ib[(r0 + sr) * 1024 + x * 4];
  }
  __syncthreads();
  #pragma unroll
  for (int p = 0; p < 4; p++) {
    int c = y + p * 16;
    bf16x4 o = {t[x * 4 + 0][c], t[x * 4 + 1][c], t[x * 4 + 2][c], t[x * 4 + 3][c]};
    *(bf16x4*)&ob[(long)c * 1024 + r0 + x * 4] = o;
  }
}

// ---------------- generic NT GEMM (m97 structure + T1 swizzle) ----------------
template <int BM, int BN, int WM, int WN, bool RELU, bool PERM, typename OutT>
__global__ __launch_bounds__(256) void k_gemm_nt(
    const bf16* __restrict__ A, const bf16* __restrict__ Bp,
    OutT* __restrict__ C, const float* __restrict__ bias,
    int K, long lda, long ldb, long ldc, float alpha, int zdiv,
    long sA1, long sA0, long sB1, long sB0, long sC1, long sC0,
    long sBias1, long sBias0) {
  constexpr int BK = 32;
  constexpr int WTM = BM / WM, WTN = BN / WN, MR = WTM / 16, NR = WTN / 16;
  constexpr int AISS = BM * BK / 2048;
  constexpr int BISS = BN * BK / 2048;
  __shared__ bf16 sa[BM * BK];
  __shared__ bf16 sb[BN * BK];
  const int nwg = gridDim.x * gridDim.y * gridDim.z;
  const int bid = blockIdx.x + gridDim.x * (blockIdx.y + gridDim.y * blockIdx.z);
  const int lid = xcd_swz(bid, nwg);
  const int bx = lid % gridDim.x;
  const int rem = lid / gridDim.x;
  const int by = rem % gridDim.y;
  const int z = rem / gridDim.y;
  const int zh = z / zdiv, zl = z - zh * zdiv;
  const bf16* Ab = A + zh * sA1 + zl * sA0 + (long)by * BM * lda;
  const bf16* Bb = Bp + zh * sB1 + zl * sB0 + (long)bx * BN * ldb;
  const int tid = threadIdx.x, lane = tid & 63, wid = tid >> 6;
  const int wm = wid / WN, wn = wid % WN;

  const int srow = tid >> 2;
  const int scol = (tid & 3) * 8;
  const bf16* aptr[AISS];
  bf16* aldst[AISS];
  #pragma unroll
  for (int i = 0; i < AISS; i++) {
    aptr[i] = Ab + (long)(srow + i * 64) * lda + scol;
    aldst[i] = &sa[i * 2048 + (wid << 9)];
  }
  const bf16* bptr[BISS];
  bf16* bldst[BISS];
  #pragma unroll
  for (int i = 0; i < BISS; i++) {
    bptr[i] = Bb + (long)(srow + i * 64) * ldb + scol;
    bldst[i] = &sb[i * 2048 + (wid << 9)];
  }

  f32x4 acc[MR][NR] = {};
  const int rA = wm * WTM + (lane & 15);
  const int rB = wn * WTN + (lane & 15);
  const int kk = (lane >> 4) * 8;

  for (int k0 = 0; k0 < K; k0 += BK) {
    #pragma unroll
    for (int i = 0; i < AISS; i++) GLOAD16(aptr[i] + k0, aldst[i]);
    #pragma unroll
    for (int i = 0; i < BISS; i++) GLOAD16(bptr[i] + k0, bldst[i]);
    __syncthreads();
    bf16x8 af[MR], bfr[NR];
    #pragma unroll
    for (int mi = 0; mi < MR; mi++) af[mi] = *(const bf16x8*)&sa[(rA + mi * 16) * BK + kk];
    #pragma unroll
    for (int ni = 0; ni < NR; ni++) bfr[ni] = *(const bf16x8*)&sb[(rB + ni * 16) * BK + kk];
    #pragma unroll
    for (int mi = 0; mi < MR; mi++)
      #pragma unroll
      for (int ni = 0; ni < NR; ni++)
        acc[mi][ni] = __builtin_amdgcn_mfma_f32_16x16x32_bf16(af[mi], bfr[ni], acc[mi][ni], 0, 0, 0);
    __syncthreads();
  }
  OutT* Cb = C + zh * sC1 + zl * sC0;
  const float* biasb = bias ? (bias + zh * sBias1 + zl * sBias0) : nullptr;
  const long rowBase = (long)by * BM + wm * WTM + ((lane >> 4) * 4);
  const long colBase = (long)bx * BN + wn * WTN + (lane & 15);
  #pragma unroll
  for (int mi = 0; mi < MR; mi++) {
    #pragma unroll
    for (int ni = 0; ni < NR; ni++) {
      long col = colBase + ni * 16;
      float bv = biasb ? biasb[col] : 0.f;
      #pragma unroll
      for (int r = 0; r < 4; r++) {
        long row = rowBase + mi * 16 + r;
        long prow = PERM ? ((row & 3) * 1024 + (row >> 2)) : row;
        float v = acc[mi][ni][r] * alpha + bv;
        if (RELU) v = fmaxf(v, 0.f);
        Cb[prow * ldc + col] = (OutT)v;
      }
    }
  }
}

// ---------------- 256^2 8-phase GEMM, ks-split ds_read scheduling ------------
// Per phase: ks0 fragment reads issued PRE-barrier (wait depth ~4); ks1 reads
// issued inside the MFMA region before the ks0 sub-cluster so their LDS
// service hides under mfma-ks0 (compiler fine-grained lgkmcnt). Staging slots,
// barriers, vmcnt accounting identical to round 7/8 (proven correct).
template <bool RELU, bool PERM, typename OutT>
__global__ __launch_bounds__(512, 2) void k_gemm8p(
    const bf16* __restrict__ A, const bf16* __restrict__ Bp,
    OutT* __restrict__ C, const float* __restrict__ bias,
    int K, long lda, long ldb, long ldc, int zdiv,
    long sA1, long sA0, long sB1, long sB0, long sC1, long sC0, long sBias1) {
  __shared__ bf16 smem[65536];   // 128 KiB
  const int nwg = gridDim.x * gridDim.y * gridDim.z;
  const int bid = blockIdx.x + gridDim.x * (blockIdx.y + gridDim.y * blockIdx.z);
  const int lid = xcd_swz(bid, nwg);
  const int bx = lid % gridDim.x;
  const int rem = lid / gridDim.x;
  const int by = rem % gridDim.y;
  const int z = rem / gridDim.y;
  const int zh = z / zdiv, zl = z - zh * zdiv;
  const bf16* Ab = A + zh * sA1 + zl * sA0 + (long)by * 256 * lda;
  const bf16* Bb = Bp + zh * sB1 + zl * sB0 + (long)bx * 256 * ldb;
  const int tid = threadIdx.x, lane = tid & 63, wid = tid >> 6;
  const int wm = wid >> 2, wn = wid & 3;
  const int lane15 = lane & 15, grp = lane >> 4;
  const int s_r = (wid << 3) + (lane >> 3);
  const int s_k = ((lane & 7) ^ (lane >> 3)) << 3;
  const int ldst = wid << 9;
  const int in0 = (grp << 4) ^ ((lane & 7) << 4);
  const int in1 = (64 | (grp << 4)) ^ ((lane & 7) << 4);

  const int NT = K >> 6;
  f32x4 acc[8][4] = {};
  bf16x8 a[4][2], b[2][2][2];

  // staging base pointers (quarter offsets hoisted as SGPR loop-invariants)
  const bf16* pA0 = Ab + (long)s_r * lda + s_k;
  const bf16* pB0 = Bb + (long)s_r * ldb + s_k;

  auto stageA = [&](int q, long koff, int cb) {
    GLOAD16(pA0 + (long)(q << 6) * lda + koff, &smem[cb + (q << 12) + ldst]);
  };
  auto stageB = [&](int q, long koff, int cb) {
    GLOAD16(pB0 + (long)(q << 6) * ldb + koff, &smem[cb + 16384 + (q << 12) + ldst]);
  };
  auto loadA_ks = [&](int mh, int ks, int cb) {
    const int inx = ks ? in1 : in0;
    #pragma unroll
    for (int mi2 = 0; mi2 < 4; mi2++) {
      int r = wm * 128 + mh * 64 + mi2 * 16 + lane15;
      a[mi2][ks] = *(const bf16x8*)&smem[cb + (r << 6) + (inx >> 1)];
    }
  };
  auto loadB_ks = [&](int nh, int ks, int cb) {
    const int inx = ks ? in1 : in0;
    #pragma unroll
    for (int ni2 = 0; ni2 < 2; ni2++) {
      int c = wn * 64 + nh * 32 + ni2 * 16 + lane15;
      b[nh][ni2][ks] = *(const bf16x8*)&smem[cb + 16384 + (c << 6) + (inx >> 1)];
    }
  };
  auto mfmaQ = [&](int mh, int nh) {
    __builtin_amdgcn_s_setprio(1);
    #pragma unroll
    for (int ks = 0; ks < 2; ks++)
      #pragma unroll
      for (int mi2 = 0; mi2 < 4; mi2++)
        #pragma unroll
        for (int ni2 = 0; ni2 < 2; ni2++)
          acc[mh * 4 + mi2][nh * 2 + ni2] = __builtin_amdgcn_mfma_f32_16x16x32_bf16(
              a[mi2][ks], b[nh][ni2][ks], acc[mh * 4 + mi2][nh * 2 + ni2], 0, 0, 0);
    __builtin_amdgcn_s_setprio(0);
  };

  // prologue: stage tiles 0 (buf0) and 1 (buf1); read tile0 b0
  #pragma unroll
  for (int q = 0; q < 4; q++) {
    stageA(q, 0, 0);
    stageB(q, 0, 0);
  }
  #pragma unroll
  for (int q = 0; q < 4; q++) {
    stageA(q, 64, 32768);
    stageB(q, 64, 32768);
  }
  asm volatile("s_waitcnt vmcnt(8)" ::: "memory");
  BAR();
  loadB_ks(0, 0, 0);
  loadB_ks(0, 1, 0);

  long koff = 128;
  for (int t = 0; t < NT; t++) {
    const int cb = (t & 1) << 15;
    const bool dostage = (t + 2) < NT;
    const bool doread = (t + 1) < NT;
    // P1: aE-ks0 pre-barrier; aE-ks1 + b1 under mfma(0,0)
    loadA_ks(0, 0, cb);
    BAR();
    loadA_ks(0, 1, cb);
    loadB_ks(1, 0, cb);
    loadB_ks(1, 1, cb);
    mfmaQ(0, 0);
    BAR();
    // P2: stage A-q0,q2 (freed by P1 aE read)
    if (dostage) { stageA(0, koff, cb); stageA(2, koff, cb); }
    BAR();
    mfmaQ(0, 1);
    BAR();
    // P3: aO-ks0 pre-barrier; stage B q0-q3 (freed after P2); aO-ks1 under mfma(1,0)
    loadA_ks(1, 0, cb);
    if (dostage) {
      stageB(0, koff, cb); stageB(1, koff, cb);
      stageB(2, koff, cb); stageB(3, koff, cb);
    }
    BAR();
    loadA_ks(1, 1, cb);
    mfmaQ(1, 0);
    BAR();
    // P4: stage A-q1,q3 (freed by P3 aO read); counted vmcnt; next b0 under mfma(1,1)
    if (dostage) {
      stageA(1, koff, cb); stageA(3, koff, cb);
      asm volatile("s_waitcnt vmcnt(8)" ::: "memory");
    } else if (doread) {
      asm volatile("s_waitcnt vmcnt(0)" ::: "memory");
    }
    BAR();
    if (doread) {
      loadB_ks(0, 0, cb ^ 32768);
      loadB_ks(0, 1, cb ^ 32768);
    }
    mfmaQ(1, 1);
    BAR();
    koff += 64;
  }

  // epilogue: direct stores (proven conflict-free)
  OutT* Cb = C + zh * sC1 + zl * sC0;
  const float* biasb = bias ? (bias + zh * sBias1) : nullptr;
  float bv[4];
  #pragma unroll
  for (int ni = 0; ni < 4; ni++)
    bv[ni] = biasb ? biasb[(long)bx * 256 + wn * 64 + ni * 16 + lane15] : 0.f;
  const long rowBase = (long)by * 256 + wm * 128 + grp * 4;
  const long colBase = (long)bx * 256 + wn * 64 + lane15;
  #pragma unroll
  for (int mi = 0; mi < 8; mi++) {
    #pragma unroll
    for (int ni = 0; ni < 4; ni++) {
      long col = colBase + ni * 16;
      #pragma unroll
      for (int r = 0; r < 4; r++) {
        long row = rowBase + mi * 16 + r;
        long prow = PERM ? ((row & 3) * 1024 + (row >> 2)) : row;
        float v = acc[mi][ni][r] + bv[ni];
        if (RELU) v = fmaxf(v, 0.f);
        Cb[prow * ldc + col] = (OutT)v;
      }
    }
  }
}

// ---------------- fused flash attention (dense [B][T][1024] q/k slices) -----
__global__ __launch_bounds__(256) void k_flash(
    const bf16* __restrict__ q, const bf16* __restrict__ kk,
    const bf16* __restrict__ vt, bf16* __restrict__ ao) {
  __shared__ bf16 kt[2][2048];
  __shared__ bf16 vtt[2][2048];
  __shared__ bf16 p_lds[4][32 * 72];
  const int nwg = gridDim.x * gridDim.y;
  const int bid = blockIdx.x + gridDim.x * blockIdx.y;
  const int lid = xcd_swz(bid, nwg);
  const int qt = lid & 7;
  const int bh = lid >> 3;
  const int b = bh >> 4, h = bh & 15;
  const int tid = threadIdx.x, lane = tid & 63, wid = tid >> 6;
  const int colLane = lane & 15, grp = lane >> 4;
  const bf16* qb = q + (long)b * 1048576 + h * 64;
  const bf16* kb = kk + (long)b * 1048576 + h * 64;
  const bf16* vb = vt + (long)bh * 65536;

  bf16x8 qf[2][2];
  const int qrow0 = qt * 128 + wid * 32 + colLane;
  #pragma unroll
  for (int mi = 0; mi < 2; mi++)
    #pragma unroll
    for (int ks = 0; ks < 2; ks++)
      qf[mi][ks] = *(const bf16x8*)&qb[(long)(qrow0 + mi * 16) * 1024 + ks * 32 + grp * 8];

  const int srow = tid >> 2;
  const int scol = (tid & 3) * 8;

  f32x4 oacc[2][4] = {};
  float m_[2][4], l_[2][4];
  #pragma unroll
  for (int mi = 0; mi < 2; mi++)
    #pragma unroll
    for (int r = 0; r < 4; r++) { m_[mi][r] = -INFINITY; l_[mi][r] = 0.f; }
  bf16* pl = &p_lds[wid][0];

  for (int s0 = 0; s0 < 1024; s0 += 64) {
    GLOAD16(&kb[(long)(s0 + srow) * 1024 + scol], &kt[0][wid << 9]);
    GLOAD16(&kb[(long)(s0 + srow) * 1024 + 32 + scol], &kt[1][wid << 9]);
    GLOAD16(&vb[(long)srow * 1024 + s0 + scol], &vtt[0][wid << 9]);
    GLOAD16(&vb[(long)srow * 1024 + s0 + 32 + scol], &vtt[1][wid << 9]);
    __syncthreads();

    f32x4 sacc[2][4] = {};
    bf16x8 kf[4][2];
    #pragma unroll
    for (int ni = 0; ni < 4; ni++)
      #pragma unroll
      for (int ks = 0; ks < 2; ks++)
        kf[ni][ks] = *(const bf16x8*)&kt[ks][(colLane + ni * 16) * 32 + grp * 8];
    #pragma unroll
    for (int ks = 0; ks < 2; ks++)
      #pragma unroll
      for (int mi = 0; mi < 2; mi++)
        #pragma unroll
        for (int ni = 0; ni < 4; ni++)
          sacc[mi][ni] = __builtin_amdgcn_mfma_f32_16x16x32_bf16(qf[mi][ks], kf[ni][ks], sacc[mi][ni], 0, 0, 0);

    float mnew[2][4], sc[2][4], psum[2][4];
    #pragma unroll
    for (int mi = 0; mi < 2; mi++)
      #pragma unroll
      for (int r = 0; r < 4; r++) {
        float vx = fmaxf(fmaxf(sacc[mi][0][r], sacc[mi][1][r]),
                         fmaxf(sacc[mi][2][r], sacc[mi][3][r])) * 0.125f;
        #pragma unroll
        for (int o = 1; o < 16; o <<= 1) vx = fmaxf(vx, __shfl_xor(vx, o));
        float mn = fmaxf(m_[mi][r], vx);
        sc[mi][r] = __expf(m_[mi][r] - mn);
        m_[mi][r] = mn; mnew[mi][r] = mn;
        l_[mi][r] *= sc[mi][r];
        psum[mi][r] = 0.f;
      }
    #pragma unroll
    for (int mi = 0; mi < 2; mi++)
      #pragma unroll
      for (int ni = 0; ni < 4; ni++)
        #pragma unroll
        for (int r = 0; r < 4; r++)
          oacc[mi][ni][r] *= sc[mi][r];
    #pragma unroll
    for (int mi = 0; mi < 2; mi++)
      #pragma unroll
      for (int ni = 0; ni < 4; ni++)
        #pragma unroll
        for (int r = 0; r < 4; r++) {
          float p = __expf(sacc[mi][ni][r] * 0.125f - mnew[mi][r]);
          psum[mi][r] += p;
          pl[(mi * 16 + grp * 4 + r) * 72 + ni * 16 + colLane] = (bf16)p;
        }
    #pragma unroll
    for (int mi = 0; mi < 2; mi++)
      #pragma unroll
      for (int r = 0; r < 4; r++) {
        float ps = psum[mi][r];
        #pragma unroll
        for (int o = 1; o < 16; o <<= 1) ps += __shfl_xor(ps, o);
        l_[mi][r] += ps;
      }

    bf16x8 pa[2][2], vf[4][2];
    #pragma unroll
    for (int mi = 0; mi < 2; mi++)
      #pragma unroll
      for (int ks = 0; ks < 2; ks++)
        pa[mi][ks] = *(const bf16x8*)&pl[(colLane + mi * 16) * 72 + ks * 32 + grp * 8];
    #pragma unroll
    for (int ni = 0; ni < 4; ni++)
      #pragma unroll
      for (int ks = 0; ks < 2; ks++)
        vf[ni][ks] = *(const bf16x8*)&vtt[ks][(colLane + ni * 16) * 32 + grp * 8];
    #pragma unroll
    for (int ks = 0; ks < 2; ks++)
      #pragma unroll
      for (int mi = 0; mi < 2; mi++)
        #pragma unroll
        for (int ni = 0; ni < 4; ni++)
          oacc[mi][ni] = __builtin_amdgcn_mfma_f32_16x16x32_bf16(pa[mi][ks], vf[ni][ks], oacc[mi][ni], 0, 0, 0);
    __syncthreads();
  }

  #pragma unroll
  for (int mi = 0; mi < 2; mi++)
    #pragma unroll
    for (int r = 0; r < 4; r++) {
      float inv = 1.f / l_[mi][r];
      int t = qt * 128 + wid * 32 + mi * 16 + grp * 4 + r;
      long n = (long)t * 4 + b;
      #pragma unroll
      for (int ni = 0; ni < 4; ni++)
        ao[n * 1024 + h * 64 + ni * 16 + colLane] = (bf16)(oacc[mi][ni][r] * inv);
    }
}

// ---------------- residual add + LayerNorm (float4) ----------------
__global__ __launch_bounds__(256) void k_add_ln(const float* __restrict__ a, const float* __restrict__ b,
                                                const float* __restrict__ g, const float* __restrict__ be,
                                                float* __restrict__ out, bf16* __restrict__ outb) {
  long row = blockIdx.x;
  int tid = threadIdx.x;
  float4 va = ((const float4*)(a + row * 1024))[tid];
  float4 vb = ((const float4*)(b + row * 1024))[tid];
  float v[4] = {va.x + vb.x, va.y + vb.y, va.z + vb.z, va.w + vb.w};
  float s = v[0] + v[1] + v[2] + v[3];
  float sq = v[0] * v[0] + v[1] * v[1] + v[2] * v[2] + v[3] * v[3];
  #pragma unroll
  for (int o = 32; o; o >>= 1) { s += __shfl_xor(s, o); sq += __shfl_xor(sq, o); }
  __shared__ float r1[4], r2[4];
  int wid = tid >> 6;
  if ((tid & 63) == 0) { r1[wid] = s; r2[wid] = sq; }
  __syncthreads();
  s = r1[0] + r1[1] + r1[2] + r1[3];
  sq = r2[0] + r2[1] + r2[2] + r2[3];
  float mu = s * (1.f / 1024.f);
  float var = sq * (1.f / 1024.f) - mu * mu;
  float rstd = rsqrtf(var + 1e-5f);
  float4 vg = ((const float4*)g)[tid];
  float4 vbe = ((const float4*)be)[tid];
  float y0 = (v[0] - mu) * rstd * vg.x + vbe.x;
  float y1 = (v[1] - mu) * rstd * vg.y + vbe.y;
  float y2 = (v[2] - mu) * rstd * vg.z + vbe.z;
  float y3 = (v[3] - mu) * rstd * vg.w + vbe.w;
  ((float4*)(out + row * 1024))[tid] = make_float4(y0, y1, y2, y3);
  if (outb) {
    bf16x4 o = {(bf16)y0, (bf16)y1, (bf16)y2, (bf16)y3};
    ((bf16x4*)(outb + row * 1024))[tid] = o;
  }
}

// ---------------- MoE gating ----------------
__global__ __launch_bounds__(256) void k_gate(const float* __restrict__ x, const float* __restrict__ wg,
                                              int* __restrict__ e1, int* __restrict__ e2,
                                              float* __restrict__ g1, float* __restrict__ g2) {
  int n = blockIdx.x * 4 + (threadIdx.x >> 6);
  int lane = threadIdx.x & 63;
  const float* xr = x + (long)n * 1024;
  float acc[8] = {0.f, 0.f, 0.f, 0.f, 0.f, 0.f, 0.f, 0.f};
  for (int i = 0; i < 16; i++) {
    float xv = xr[i * 64 + lane];
    const float* wr = wg + (long)(i * 64 + lane) * 8;
    float4 w0 = *(const float4*)wr;
    float4 w1v = *(const float4*)(wr + 4);
    acc[0] += xv * w0.x; acc[1] += xv * w0.y; acc[2] += xv * w0.z; acc[3] += xv * w0.w;
    acc[4] += xv * w1v.x; acc[5] += xv * w1v.y; acc[6] += xv * w1v.z; acc[7] += xv * w1v.w;
  }
  #pragma unroll
  for (int e = 0; e < 8; e++)
    #pragma unroll
    for (int o = 32; o; o >>= 1) acc[e] += __shfl_xor(acc[e], o);
  if (lane == 0) {
    int i1 = 0; float b1v = acc[0];
    #pragma unroll
    for (int e = 1; e < 8; e++) if (acc[e] > b1v) { b1v = acc[e]; i1 = e; }
    int i2 = -1; float b2v = -INFINITY;
    #pragma unroll
    for (int e = 0; e < 8; e++) if (e != i1 && acc[e] > b2v) { b2v = acc[e]; i2 = e; }
    float den = 0.f;
    #pragma unroll
    for (int e = 0; e < 8; e++) den += __expf(acc[e] - b1v);
    float gg1 = 1.f / den;
    float gg2 = __expf(b2v - b1v) / den;
    float dn = gg1 + gg2 + 1e-9f;
    e1[n] = i1; e2[n] = i2; g1[n] = gg1 / dn; g2[n] = gg2 / dn;
  }
}

// ---------------- capacity positions: one block per expert, ordered scan ----
__global__ __launch_bounds__(256) void k_positions(const int* __restrict__ e1, const int* __restrict__ e2,
                                                   const float* __restrict__ g1, const float* __restrict__ g2,
                                                   int* __restrict__ d1, int* __restrict__ d2,
                                                   float* __restrict__ s1, float* __restrict__ s2) {
  const int e = blockIdx.x;
  const int tid = threadIdx.x, lane = tid & 63, wid = tid >> 6;
  __shared__ int wsum[4];
  int f[16];
  int cnt = 0;
  #pragma unroll
  for (int i = 0; i < 16; i++) { f[i] = (e1[tid * 16 + i] == e) ? 1 : 0; cnt += f[i]; }
  int inc = cnt;
  #pragma unroll
  for (int o = 1; o < 64; o <<= 1) { int v = __shfl_up(inc, o); if (lane >= o) inc += v; }
  if (lane == 63) wsum[wid] = inc;
  __syncthreads();
  int base = inc - cnt;
  for (int w = 0; w < wid; w++) base += wsum[w];
  const int total1 = wsum[0] + wsum[1] + wsum[2] + wsum[3];
  int run = base;
  #pragma unroll
  for (int i = 0; i < 16; i++) {
    int n = tid * 16 + i;
    if (f[i]) {
      int p = run++;
      d1[n] = e * CAP_ + (p < CAP_ ? p : CAP_ - 1);
      s1[n] = (p < CAP_) ? g1[n] : 0.f;
    }
  }
  cnt = 0;
  #pragma unroll
  for (int i = 0; i < 16; i++) { f[i] = (e2[tid * 16 + i] == e) ? 1 : 0; cnt += f[i]; }
  inc = cnt;
  #pragma unroll
  for (int o = 1; o < 64; o <<= 1) { int v = __shfl_up(inc, o); if (lane >= o) inc += v; }
  __syncthreads();
  if (lane == 63) wsum[wid] = inc;
  __syncthreads();
  base = inc - cnt + total1;
  for (int w = 0; w < wid; w++) base += wsum[w];
  run = base;
  #pragma unroll
  for (int i = 0; i < 16; i++) {
    int n = tid * 16 + i;
    if (f[i]) {
      int p = run++;
      d2[n] = e * CAP_ + (p < CAP_ ? p : CAP_ - 1);
      s2[n] = (p < CAP_) ? g2[n] : 0.f;
    }
  }
}

// ---------------- scatter tokens into expert buffers ----------------
__global__ __launch_bounds__(256) void k_scatter(const float* __restrict__ x, const int* __restrict__ d1,
                                                 const int* __restrict__ d2, const float* __restrict__ s1,
                                                 const float* __restrict__ s2, bf16* __restrict__ buf) {
  int n = blockIdx.x;
  int tid = threadIdx.x;
  float4 v = ((const float4*)(x + (long)n * 1024))[tid];
  bf16x4 o = {(bf16)v.x, (bf16)v.y, (bf16)v.z, (bf16)v.w};
  if (s1[n] != 0.f) ((bf16x4*)(buf + (long)d1[n] * 1024))[tid] = o;
  if (s2[n] != 0.f) ((bf16x4*)(buf + (long)d2[n] * 1024))[tid] = o;
}

// ---------------- gather expert outputs (2 bf16 partials + b2) + LN3 --------
__global__ __launch_bounds__(256) void k_gather_ln(const float* __restrict__ x,
                                                   const bf16* __restrict__ p0, const bf16* __restrict__ p1,
                                                   const float* __restrict__ b2,
                                                   const int* __restrict__ d1, const int* __restrict__ d2,
                                                   const float* __restrict__ s1, const float* __restrict__ s2,
                                                   const float* __restrict__ g, const float* __restrict__ be,
                                                   float* __restrict__ out) {
  long n = blockIdx.x;
  int tid = threadIdx.x;
  float a1 = s1[n], a2 = s2[n];
  long i1 = (long)d1[n] * 1024, i2 = (long)d2[n] * 1024;
  long e1b = (long)(d1[n] >> 10) * 1024, e2b = (long)(d2[n] >> 10) * 1024;
  float4 vx = ((const float4*)(x + n * 1024))[tid];
  bf16x4 q10 = *(const bf16x4*)&p0[i1 + tid * 4];
  bf16x4 q11 = *(const bf16x4*)&p1[i1 + tid * 4];
  bf16x4 q20 = *(const bf16x4*)&p0[i2 + tid * 4];
  bf16x4 q21 = *(const bf16x4*)&p1[i2 + tid * 4];
  float4 vb1 = ((const float4*)(b2 + e1b))[tid];
  float4 vb2 = ((const float4*)(b2 + e2b))[tid];
  float v[4];
  float xs[4] = {vx.x, vx.y, vx.z, vx.w};
  float b1a[4] = {vb1.x, vb1.y, vb1.z, vb1.w};
  float b2a[4] = {vb2.x, vb2.y, vb2.z, vb2.w};
  float s = 0.f, sq = 0.f;
  #pragma unroll
  for (int i = 0; i < 4; i++) {
    float r1v = (float)q10[i] + (float)q11[i] + b1a[i];
    float r2v = (float)q20[i] + (float)q21[i] + b2a[i];
    float y = xs[i] + a1 * r1v + a2 * r2v;
    v[i] = y; s += y; sq += y * y;
  }
  #pragma unroll
  for (int o = 32; o; o >>= 1) { s += __shfl_xor(s, o); sq += __shfl_xor(sq, o); }
  __shared__ float r1[4], r2[4];
  int wid = tid >> 6;
  if ((tid & 63) == 0) { r1[wid] = s; r2[wid] = sq; }
  __syncthreads();
  s = r1[0] + r1[1] + r1[2] + r1[3];
  sq = r2[0] + r2[1] + r2[2] + r2[3];
  float mu = s * (1.f / 1024.f);
  float var = sq * (1.f / 1024.f) - mu * mu;
  float rstd = rsqrtf(var + 1e-5f);
  float4 vg = ((const float4*)g)[tid];
  float4 vbe = ((const float4*)be)[tid];
  float ga[4] = {vg.x, vg.y, vg.z, vg.w};
  float ba[4] = {vbe.x, vbe.y, vbe.z, vbe.w};
  float4 o;
  o.x = (v[0] - mu) * rstd * ga[0] + ba[0];
  o.y = (v[1] - mu) * rstd * ga[1] + ba[1];
  o.z = (v[2] - mu) * rstd * ga[2] + ba[2];
  o.w = (v[3] - mu) * rstd * ga[3] + ba[3];
  ((float4*)(out + n * 1024))[tid] = o;
}

// ---------------------------------------------------------------------------
extern "C" void kernel_launch(void* const* d_in, const int* in_sizes, int n_in,
                              void* d_out, int out_size, void* d_ws, size_t ws_size,
                              hipStream_t stream) {
  const float* tgt      = (const float*)d_in[0];
  const float* memory   = (const float*)d_in[1];
  const float* sa_in_w  = (const float*)d_in[2];
  const float* sa_in_b  = (const float*)d_in[3];
  const float* sa_out_w = (const float*)d_in[4];
  const float* sa_out_b = (const float*)d_in[5];
  const float* ca_in_w  = (const float*)d_in[6];
  const float* ca_in_b  = (const float*)d_in[7];
  const float* ca_out_w = (const float*)d_in[8];
  const float* ca_out_b = (const float*)d_in[9];
  const float* ln1_g    = (const float*)d_in[10];
  const float* ln1_b    = (const float*)d_in[11];
  const float* ln2_g    = (const float*)d_in[12];
  const float* ln2_b    = (const float*)d_in[13];
  const float* ln3_g    = (const float*)d_in[14];
  const float* ln3_b    = (const float*)d_in[15];
  const float* wg       = (const float*)d_in[16];
  const float* w1       = (const float*)d_in[17];
  const float* b1       = (const float*)d_in[18];
  const float* w2       = (const float*)d_in[19];
  const float* b2       = (const float*)d_in[20];

  char* ws = (char*)d_ws;
  auto B16 = [&](long o) { return (bf16*)(ws + o); };
  auto F32 = [&](long o) { return (float*)(ws + o); };
  auto I32 = [&](long o) { return (int*)(ws + o); };

  const dim3 blk256(256), blk512(512);

  // ---- phase 0: conversions to bf16 (single launch)
  k_cvt6<<<16384, blk256, 0, stream>>>(sa_in_w, sa_out_w, ca_in_w, ca_out_w, tgt, memory,
                                       B16(OFF_WSAIN), B16(OFF_WSAOUT), B16(OFF_WCAIN),
                                       B16(OFF_WCAOUT), B16(OFF_BTGT), B16(OFF_BMEM));

  // ---- phase 1: self-attention
  k_gemm8p<false, true, bf16><<<dim3(4, 16, 3), blk512, 0, stream>>>(
      B16(OFF_BTGT), B16(OFF_WSAIN), B16(OFF_QS), sa_in_b,
      1024, 1024, 1024, 1024, 1,
      0, 0, 1048576, 0, 4194304, 0, 1024);
  k_extract_vt<<<dim3(16, 64), blk256, 0, stream>>>(B16(OFF_VS), B16(OFF_VT));
  k_flash<<<dim3(8, 64), blk256, 0, stream>>>(B16(OFF_QS), B16(OFF_KS), B16(OFF_VT), B16(OFF_AO));
  k_gemm_nt<128, 64, 4, 1, false, false, float><<<dim3(16, 32, 1), blk256, 0, stream>>>(
      B16(OFF_AO), B16(OFF_WSAOUT), F32(OFF_PROJ), sa_out_b,
      1024, 1024, 1024, 1024, 1.f, 1, 0, 0, 0, 0, 0, 0, 0, 0);
  k_add_ln<<<4096, blk256, 0, stream>>>(tgt, F32(OFF_PROJ), ln1_g, ln1_b, F32(OFF_X1), B16(OFF_BTGT));

  // ---- phase 2: cross-attention
  k_gemm_nt<128, 64, 4, 1, false, true, bf16><<<dim3(16, 32, 1), blk256, 0, stream>>>(
      B16(OFF_BTGT), B16(OFF_WCAIN), B16(OFF_QS), ca_in_b,
      1024, 1024, 1024, 1024, 1.f, 1, 0, 0, 0, 0, 0, 0, 0, 0);
  k_gemm_nt<128, 64, 4, 1, false, true, bf16><<<dim3(16, 32, 2), blk256, 0, stream>>>(
      B16(OFF_BMEM), B16(OFF_WCAIN) + 1024L * 1024, B16(OFF_KS), ca_in_b + 1024,
      1024, 1024, 1024, 1024, 1.f, 1,
      0, 0, 1048576, 0, 4194304, 0, 1024, 0);
  k_extract_vt<<<dim3(16, 64), blk256, 0, stream>>>(B16(OFF_VS), B16(OFF_VT));
  k_flash<<<dim3(8, 64), blk256, 0, stream>>>(B16(OFF_QS), B16(OFF_KS), B16(OFF_VT), B16(OFF_AO));
  k_gemm_nt<128, 64, 4, 1, false, false, float><<<dim3(16, 32, 1), blk256, 0, stream>>>(
      B16(OFF_AO), B16(OFF_WCAOUT), F32(OFF_PROJ), ca_out_b,
      1024, 1024, 1024, 1024, 1.f, 1, 0, 0, 0, 0, 0, 0, 0, 0);
  k_add_ln<<<4096, blk256, 0, stream>>>(F32(OFF_X1), F32(OFF_PROJ), ln2_g, ln2_b, F32(OFF_X2), (bf16*)nullptr);

  // ---- phase 3: MoE
  k_gate<<<1024, blk256, 0, stream>>>(F32(OFF_X2), wg, I32(OFF_E1), I32(OFF_E2), F32(OFF_G1), F32(OFF_G2));
  k_positions<<<8, blk256, 0, stream>>>(I32(OFF_E1), I32(OFF_E2), F32(OFF_G1), F32(OFF_G2),
                                        I32(OFF_D1), I32(OFF_D2), F32(OFF_S1), F32(OFF_S2));
  k_scatter<<<4096, blk256, 0, stream>>>(F32(OFF_X2), I32(OFF_D1), I32(OFF_D2),
                                         F32(OFF_S1), F32(OFF_S2), B16(OFF_QKV));
  k_transpose_f32_bf16<<<dim3(64, 16, 8), blk256, 0, stream>>>(w1, B16(OFF_SCORES), 1024, 4096);
  k_gemm8p<true, false, bf16><<<dim3(16, 4, 8), blk512, 0, stream>>>(
      B16(OFF_QKV), B16(OFF_SCORES), B16(OFF_H), b1,
      1024, 1024, 1024, 4096, 1,
      1048576, 0, 4194304, 0, 4194304, 0, 4096);
  k_transpose_f32_bf16<<<dim3(16, 64, 8), blk256, 0, stream>>>(w2, B16(OFF_SCORES), 4096, 1024);
  k_gemm8p<false, false, bf16><<<dim3(4, 4, 16), blk512, 0, stream>>>(
      B16(OFF_H), B16(OFF_SCORES), B16(OFF_PROJ), nullptr,
      2048, 4096, 4096, 1024, 2,
      4194304, 2048, 4194304, 2048, 1048576, (OFF_EO1 - OFF_PROJ) / 2, 0);
  k_gather_ln<<<4096, blk256, 0, stream>>>(F32(OFF_X2), B16(OFF_PROJ), B16(OFF_EO1), b2,
                                           I32(OFF_D1), I32(OFF_D2),
                                           F32(OFF_S1), F32(OFF_S2), ln3_g, ln3_b, (float*)d_out);

  (void)in_sizes; (void)n_in; (void)out_size; (void)ws_size;
}

// Round 11
// 549.585 us; speedup vs baseline: 1.0032x; 1.0032x over previous
//
#include <hip/hip_runtime.h>
#include <hip/hip_bf16.h>

// ---------------------------------------------------------------------------
// TransformerMoEDecoderLayer: SA -> add+LN -> CA -> add+LN -> MoE top2 -> add+LN
// T=S=1024, B=4, D=1024, H=16, HD=64, F=4096, E=8, N=4096, CAP=1024
// Round 11: full revert to round-9 GEMM/flash (r10's combined change broke
//           correctness); merged CA q/k/v projection launch; gate fused into
//           the second add+LN.
// ---------------------------------------------------------------------------

typedef __bf16 bf16;
typedef __bf16 bf16x2 __attribute__((ext_vector_type(2)));
typedef __bf16 bf16x4 __attribute__((ext_vector_type(4)));
typedef __bf16 bf16x8 __attribute__((ext_vector_type(8)));
typedef float  f32x4  __attribute__((ext_vector_type(4)));

static_assert(sizeof(bf16) == 2, "bf16 size");

#define CAP_ 1024

#define GLOAD16(g, l)                                                  \
  __builtin_amdgcn_global_load_lds(                                    \
      (const __attribute__((address_space(1))) unsigned int*)(g),      \
      (__attribute__((address_space(3))) unsigned int*)(l), 16, 0, 0)

#define BAR() do { asm volatile("" ::: "memory"); __builtin_amdgcn_s_barrier(); asm volatile("" ::: "memory"); } while (0)

// ---------------- workspace layout (bytes) ----------------
static const long OFF_WSAIN  = 0L;                         // bf16 [3072][1024]
static const long OFF_WSAOUT = 6291456L;                   // bf16 [1024][1024]
static const long OFF_WCAIN  = 8388608L;                   // bf16 [3072][1024]
static const long OFF_WCAOUT = 14680064L;                  // bf16 [1024][1024]
static const long OFF_BTGT   = 16777216L;                  // bf16 [4096][1024] (later x1b)
static const long OFF_BMEM   = 25165824L;                  // bf16 [4096][1024]
static const long OFF_QKV    = 33554432L;                  // 3 slices bf16 [4][1024][1024]; phase3: expert buf + eo partial1
static const long OFF_QS     = OFF_QKV;
static const long OFF_KS     = OFF_QKV + 8388608L;
static const long OFF_VS     = OFF_QKV + 16777216L;
static const long OFF_EO1    = 33554432L;                  // bf16 [8][1024][1024] partial1
static const long OFF_VT     = 58720256L;                  // bf16 [64][64][1024]
static const long OFF_AO     = 67108864L;                  // bf16 [4096][1024]
static const long OFF_PROJ   = 75497472L;                  // f32 [4096][1024]; phase3: eo partial0 bf16
static const long OFF_X1     = 92274688L;                  // f32 [4096][1024]
static const long OFF_X2     = 109051904L;                 // f32 [4096][1024]
static const long OFF_SCORES = 125829120L;                 // phase3: w1t/w2t 64MB
static const long OFF_H      = OFF_SCORES + 67108864L;     // bf16 [8][1024][4096]
static const long OFF_GATE   = 260046848L;
static const long OFF_E1   = OFF_GATE;
static const long OFF_E2   = OFF_GATE + 16384L;
static const long OFF_G1   = OFF_GATE + 32768L;
static const long OFF_G2   = OFF_GATE + 49152L;
static const long OFF_D1   = OFF_GATE + 65536L;
static const long OFF_D2   = OFF_GATE + 81920L;
static const long OFF_S1   = OFF_GATE + 98304L;
static const long OFF_S2   = OFF_GATE + 114688L;

// T1: bijective XCD chunk swizzle (m204).
__device__ __forceinline__ int xcd_swz(int bid, int nwg) {
  int q = nwg >> 3, r = nwg & 7;
  int xcd = bid & 7, idx = bid >> 3;
  return (xcd < r ? xcd * (q + 1) : r * (q + 1) + (xcd - r) * q) + idx;
}

// ---------------- fused fp32 -> bf16 conversions ----------------
__global__ __launch_bounds__(256) void k_cvt6(
    const float* __restrict__ s0, const float* __restrict__ s1,
    const float* __restrict__ s2, const float* __restrict__ s3,
    const float* __restrict__ s4, const float* __restrict__ s5,
    bf16* __restrict__ d0, bf16* __restrict__ d1, bf16* __restrict__ d2,
    bf16* __restrict__ d3, bf16* __restrict__ d4, bf16* __restrict__ d5) {
  long b = blockIdx.x;
  const float* s; bf16* d; long off;
  if (b < 3072)       { s = s0; d = d0; off = b; }
  else if (b < 4096)  { s = s1; d = d1; off = b - 3072; }
  else if (b < 7168)  { s = s2; d = d2; off = b - 4096; }
  else if (b < 8192)  { s = s3; d = d3; off = b - 7168; }
  else if (b < 12288) { s = s4; d = d4; off = b - 8192; }
  else                { s = s5; d = d5; off = b - 12288; }
  long i = off * 256 + threadIdx.x;
  float4 v = ((const float4*)s)[i];
  bf16x4 o = {(bf16)v.x, (bf16)v.y, (bf16)v.z, (bf16)v.w};
  ((bf16x4*)d)[i] = o;
}

// ---------------- transpose fp32 [z][R][C] -> bf16 [z][C][R] ----------------
__global__ __launch_bounds__(256) void k_transpose_f32_bf16(const float* __restrict__ in,
                                                            bf16* __restrict__ out, int R, int C) {
  __shared__ float t[64][66];
  int z = blockIdx.z;
  long r0 = (long)blockIdx.y * 64, c0 = (long)blockIdx.x * 64;
  const float* ib = in + (long)z * R * C;
  bf16* ob = out + (long)z * R * C;
  int tid = threadIdx.x;
  int x = tid & 15, y = tid >> 4;
  #pragma unroll
  for (int j = 0; j < 4; j++) {
    int sr = y + j * 16;
    float4 v = *(const float4*)&ib[(r0 + sr) * C + c0 + x * 4];
    t[sr][x * 4 + 0] = v.x; t[sr][x * 4 + 1] = v.y;
    t[sr][x * 4 + 2] = v.z; t[sr][x * 4 + 3] = v.w;
  }
  __syncthreads();
  int xs = tid & 7, jj = tid >> 3;   // 8 x 32
  #pragma unroll
  for (int p = 0; p < 2; p++) {
    int c = jj + p * 32;
    bf16x8 o;
    #pragma unroll
    for (int k = 0; k < 8; k++) o[k] = (bf16)t[xs * 8 + k][c];
    *(bf16x8*)&ob[(c0 + c) * R + r0 + xs * 8] = o;
  }
}

// ---------------- extract V^T per head: [4][1024][1024] -> vt[bh][64][1024] --
__global__ __launch_bounds__(256) void k_extract_vt(const bf16* __restrict__ in,
                                                    bf16* __restrict__ out) {
  __shared__ bf16 t[64][68];
  const int bh = blockIdx.y;
  const long r0 = (long)blockIdx.x * 64;
  const int b = bh >> 4, h = bh & 15;
  const bf16* ib = in + (long)b * 1048576 + h * 64;
  bf16* ob = out + (long)bh * 65536;
  int tid = threadIdx.x;
  int x = tid & 15, y = tid >> 4;
  #pragma unroll
  for (int j = 0; j < 4; j++) {
    int sr = y + j * 16;
    *(bf16x4*)&t[sr][x * 4] = *(const bf16x4*)&ib[(r0 + sr) * 1024 + x * 4];
  }
  __syncthreads();
  #pragma unroll
  for (int p = 0; p < 4; p++) {
    int c = y + p * 16;
    bf16x4 o = {t[x * 4 + 0][c], t[x * 4 + 1][c], t[x * 4 + 2][c], t[x * 4 + 3][c]};
    *(bf16x4*)&ob[(long)c * 1024 + r0 + x * 4] = o;
  }
}

// ---------------- generic NT GEMM (m97 structure + T1 swizzle) ----------------
template <int BM, int BN, int WM, int WN, bool RELU, bool PERM, typename OutT>
__global__ __launch_bounds__(256) void k_gemm_nt(
    const bf16* __restrict__ A, const bf16* __restrict__ Bp,
    OutT* __restrict__ C, const float* __restrict__ bias,
    int K, long lda, long ldb, long ldc, float alpha, int zdiv,
    long sA1, long sA0, long sB1, long sB0, long sC1, long sC0,
    long sBias1, long sBias0) {
  constexpr int BK = 32;
  constexpr int WTM = BM / WM, WTN = BN / WN, MR = WTM / 16, NR = WTN / 16;
  constexpr int AISS = BM * BK / 2048;
  constexpr int BISS = BN * BK / 2048;
  __shared__ bf16 sa[BM * BK];
  __shared__ bf16 sb[BN * BK];
  const int nwg = gridDim.x * gridDim.y * gridDim.z;
  const int bid = blockIdx.x + gridDim.x * (blockIdx.y + gridDim.y * blockIdx.z);
  const int lid = xcd_swz(bid, nwg);
  const int bx = lid % gridDim.x;
  const int rem = lid / gridDim.x;
  const int by = rem % gridDim.y;
  const int z = rem / gridDim.y;
  const int zh = z / zdiv, zl = z - zh * zdiv;
  const bf16* Ab = A + zh * sA1 + zl * sA0 + (long)by * BM * lda;
  const bf16* Bb = Bp + zh * sB1 + zl * sB0 + (long)bx * BN * ldb;
  const int tid = threadIdx.x, lane = tid & 63, wid = tid >> 6;
  const int wm = wid / WN, wn = wid % WN;

  const int srow = tid >> 2;
  const int scol = (tid & 3) * 8;
  const bf16* aptr[AISS];
  bf16* aldst[AISS];
  #pragma unroll
  for (int i = 0; i < AISS; i++) {
    aptr[i] = Ab + (long)(srow + i * 64) * lda + scol;
    aldst[i] = &sa[i * 2048 + (wid << 9)];
  }
  const bf16* bptr[BISS];
  bf16* bldst[BISS];
  #pragma unroll
  for (int i = 0; i < BISS; i++) {
    bptr[i] = Bb + (long)(srow + i * 64) * ldb + scol;
    bldst[i] = &sb[i * 2048 + (wid << 9)];
  }

  f32x4 acc[MR][NR] = {};
  const int rA = wm * WTM + (lane & 15);
  const int rB = wn * WTN + (lane & 15);
  const int kk = (lane >> 4) * 8;

  for (int k0 = 0; k0 < K; k0 += BK) {
    #pragma unroll
    for (int i = 0; i < AISS; i++) GLOAD16(aptr[i] + k0, aldst[i]);
    #pragma unroll
    for (int i = 0; i < BISS; i++) GLOAD16(bptr[i] + k0, bldst[i]);
    __syncthreads();
    bf16x8 af[MR], bfr[NR];
    #pragma unroll
    for (int mi = 0; mi < MR; mi++) af[mi] = *(const bf16x8*)&sa[(rA + mi * 16) * BK + kk];
    #pragma unroll
    for (int ni = 0; ni < NR; ni++) bfr[ni] = *(const bf16x8*)&sb[(rB + ni * 16) * BK + kk];
    #pragma unroll
    for (int mi = 0; mi < MR; mi++)
      #pragma unroll
      for (int ni = 0; ni < NR; ni++)
        acc[mi][ni] = __builtin_amdgcn_mfma_f32_16x16x32_bf16(af[mi], bfr[ni], acc[mi][ni], 0, 0, 0);
    __syncthreads();
  }
  OutT* Cb = C + zh * sC1 + zl * sC0;
  const float* biasb = bias ? (bias + zh * sBias1 + zl * sBias0) : nullptr;
  const long rowBase = (long)by * BM + wm * WTM + ((lane >> 4) * 4);
  const long colBase = (long)bx * BN + wn * WTN + (lane & 15);
  #pragma unroll
  for (int mi = 0; mi < MR; mi++) {
    #pragma unroll
    for (int ni = 0; ni < NR; ni++) {
      long col = colBase + ni * 16;
      float bv = biasb ? biasb[col] : 0.f;
      #pragma unroll
      for (int r = 0; r < 4; r++) {
        long row = rowBase + mi * 16 + r;
        long prow = PERM ? ((row & 3) * 1024 + (row >> 2)) : row;
        float v = acc[mi][ni][r] * alpha + bv;
        if (RELU) v = fmaxf(v, 0.f);
        Cb[prow * ldc + col] = (OutT)v;
      }
    }
  }
}

// ---------------- 256^2 8-phase GEMM (round-9 proven form) ----------------
template <bool RELU, bool PERM, typename OutT>
__global__ __launch_bounds__(512, 2) void k_gemm8p(
    const bf16* __restrict__ A, const bf16* __restrict__ Bp,
    OutT* __restrict__ C, const float* __restrict__ bias,
    int K, long lda, long ldb, long ldc, int zdiv,
    long sA1, long sA0, long sB1, long sB0, long sC1, long sC0, long sBias1) {
  __shared__ bf16 smem[65536];   // 128 KiB
  const int nwg = gridDim.x * gridDim.y * gridDim.z;
  const int bid = blockIdx.x + gridDim.x * (blockIdx.y + gridDim.y * blockIdx.z);
  const int lid = xcd_swz(bid, nwg);
  const int bx = lid % gridDim.x;
  const int rem = lid / gridDim.x;
  const int by = rem % gridDim.y;
  const int z = rem / gridDim.y;
  const int zh = z / zdiv, zl = z - zh * zdiv;
  const bf16* Ab = A + zh * sA1 + zl * sA0 + (long)by * 256 * lda;
  const bf16* Bb = Bp + zh * sB1 + zl * sB0 + (long)bx * 256 * ldb;
  const int tid = threadIdx.x, lane = tid & 63, wid = tid >> 6;
  const int wm = wid >> 2, wn = wid & 3;
  const int lane15 = lane & 15, grp = lane >> 4;
  const int s_r = (wid << 3) + (lane >> 3);
  const int s_k = ((lane & 7) ^ (lane >> 3)) << 3;
  const int ldst = wid << 9;
  const int in0 = (grp << 4) ^ ((lane & 7) << 4);
  const int in1 = (64 | (grp << 4)) ^ ((lane & 7) << 4);

  const int NT = K >> 6;
  f32x4 acc[8][4] = {};
  bf16x8 a[4][2], b[2][2][2];

  const bf16* pA0 = Ab + (long)s_r * lda + s_k;
  const bf16* pB0 = Bb + (long)s_r * ldb + s_k;

  auto stageA = [&](int q, long koff, int cb) {
    GLOAD16(pA0 + (long)(q << 6) * lda + koff, &smem[cb + (q << 12) + ldst]);
  };
  auto stageB = [&](int q, long koff, int cb) {
    GLOAD16(pB0 + (long)(q << 6) * ldb + koff, &smem[cb + 16384 + (q << 12) + ldst]);
  };
  auto loadA_ks = [&](int mh, int ks, int cb) {
    const int inx = ks ? in1 : in0;
    #pragma unroll
    for (int mi2 = 0; mi2 < 4; mi2++) {
      int r = wm * 128 + mh * 64 + mi2 * 16 + lane15;
      a[mi2][ks] = *(const bf16x8*)&smem[cb + (r << 6) + (inx >> 1)];
    }
  };
  auto loadB_ks = [&](int nh, int ks, int cb) {
    const int inx = ks ? in1 : in0;
    #pragma unroll
    for (int ni2 = 0; ni2 < 2; ni2++) {
      int c = wn * 64 + nh * 32 + ni2 * 16 + lane15;
      b[nh][ni2][ks] = *(const bf16x8*)&smem[cb + 16384 + (c << 6) + (inx >> 1)];
    }
  };
  auto mfmaQ = [&](int mh, int nh) {
    __builtin_amdgcn_s_setprio(1);
    #pragma unroll
    for (int ks = 0; ks < 2; ks++)
      #pragma unroll
      for (int mi2 = 0; mi2 < 4; mi2++)
        #pragma unroll
        for (int ni2 = 0; ni2 < 2; ni2++)
          acc[mh * 4 + mi2][nh * 2 + ni2] = __builtin_amdgcn_mfma_f32_16x16x32_bf16(
              a[mi2][ks], b[nh][ni2][ks], acc[mh * 4 + mi2][nh * 2 + ni2], 0, 0, 0);
    __builtin_amdgcn_s_setprio(0);
  };

  // prologue: stage tiles 0 (buf0) and 1 (buf1); read tile0 b0
  #pragma unroll
  for (int q = 0; q < 4; q++) { stageA(q, 0, 0); stageB(q, 0, 0); }
  #pragma unroll
  for (int q = 0; q < 4; q++) { stageA(q, 64, 32768); stageB(q, 64, 32768); }
  asm volatile("s_waitcnt vmcnt(8)" ::: "memory");
  BAR();
  loadB_ks(0, 0, 0);
  loadB_ks(0, 1, 0);

  long koff = 128;
  for (int t = 0; t < NT; t++) {
    const int cb = (t & 1) << 15;
    const bool dostage = (t + 2) < NT;
    const bool doread = (t + 1) < NT;
    // P1: aE-ks0 pre-barrier; aE-ks1 + b1 under mfma(0,0)
    loadA_ks(0, 0, cb);
    BAR();
    loadA_ks(0, 1, cb);
    loadB_ks(1, 0, cb);
    loadB_ks(1, 1, cb);
    mfmaQ(0, 0);
    BAR();
    // P2: stage A-q0,q2 (freed by P1 aE read)
    if (dostage) { stageA(0, koff, cb); stageA(2, koff, cb); }
    BAR();
    mfmaQ(0, 1);
    BAR();
    // P3: aO-ks0 pre-barrier; stage B q0-q3 (freed after P2); aO-ks1 under mfma(1,0)
    loadA_ks(1, 0, cb);
    if (dostage) {
      stageB(0, koff, cb); stageB(1, koff, cb);
      stageB(2, koff, cb); stageB(3, koff, cb);
    }
    BAR();
    loadA_ks(1, 1, cb);
    mfmaQ(1, 0);
    BAR();
    // P4: stage A-q1,q3 (freed by P3 aO read); counted vmcnt; next b0 under mfma(1,1)
    if (dostage) {
      stageA(1, koff, cb); stageA(3, koff, cb);
      asm volatile("s_waitcnt vmcnt(8)" ::: "memory");
    } else if (doread) {
      asm volatile("s_waitcnt vmcnt(0)" ::: "memory");
    }
    BAR();
    if (doread) {
      loadB_ks(0, 0, cb ^ 32768);
      loadB_ks(0, 1, cb ^ 32768);
    }
    mfmaQ(1, 1);
    BAR();
    koff += 64;
  }

  // epilogue: direct stores (proven conflict-free)
  OutT* Cb = C + zh * sC1 + zl * sC0;
  const float* biasb = bias ? (bias + zh * sBias1) : nullptr;
  float bv[4];
  #pragma unroll
  for (int ni = 0; ni < 4; ni++)
    bv[ni] = biasb ? biasb[(long)bx * 256 + wn * 64 + ni * 16 + lane15] : 0.f;
  const long rowBase = (long)by * 256 + wm * 128 + grp * 4;
  const long colBase = (long)bx * 256 + wn * 64 + lane15;
  #pragma unroll
  for (int mi = 0; mi < 8; mi++) {
    #pragma unroll
    for (int ni = 0; ni < 4; ni++) {
      long col = colBase + ni * 16;
      #pragma unroll
      for (int r = 0; r < 4; r++) {
        long row = rowBase + mi * 16 + r;
        long prow = PERM ? ((row & 3) * 1024 + (row >> 2)) : row;
        float v = acc[mi][ni][r] + bv[ni];
        if (RELU) v = fmaxf(v, 0.f);
        Cb[prow * ldc + col] = (OutT)v;
      }
    }
  }
}

// ---------------- fused flash attention (round-9 proven form) ----------------
__global__ __launch_bounds__(256) void k_flash(
    const bf16* __restrict__ q, const bf16* __restrict__ kk,
    const bf16* __restrict__ vt, bf16* __restrict__ ao) {
  __shared__ bf16 kt[2][2048];
  __shared__ bf16 vtt[2][2048];
  __shared__ bf16 p_lds[4][32 * 72];
  const int nwg = gridDim.x * gridDim.y;
  const int bid = blockIdx.x + gridDim.x * blockIdx.y;
  const int lid = xcd_swz(bid, nwg);
  const int qt = lid & 7;
  const int bh = lid >> 3;
  const int b = bh >> 4, h = bh & 15;
  const int tid = threadIdx.x, lane = tid & 63, wid = tid >> 6;
  const int colLane = lane & 15, grp = lane >> 4;
  const bf16* qb = q + (long)b * 1048576 + h * 64;
  const bf16* kb = kk + (long)b * 1048576 + h * 64;
  const bf16* vb = vt + (long)bh * 65536;

  bf16x8 qf[2][2];
  const int qrow0 = qt * 128 + wid * 32 + colLane;
  #pragma unroll
  for (int mi = 0; mi < 2; mi++)
    #pragma unroll
    for (int ks = 0; ks < 2; ks++)
      qf[mi][ks] = *(const bf16x8*)&qb[(long)(qrow0 + mi * 16) * 1024 + ks * 32 + grp * 8];

  const int srow = tid >> 2;
  const int scol = (tid & 3) * 8;

  f32x4 oacc[2][4] = {};
  float m_[2][4], l_[2][4];
  #pragma unroll
  for (int mi = 0; mi < 2; mi++)
    #pragma unroll
    for (int r = 0; r < 4; r++) { m_[mi][r] = -INFINITY; l_[mi][r] = 0.f; }
  bf16* pl = &p_lds[wid][0];

  for (int s0 = 0; s0 < 1024; s0 += 64) {
    GLOAD16(&kb[(long)(s0 + srow) * 1024 + scol], &kt[0][wid << 9]);
    GLOAD16(&kb[(long)(s0 + srow) * 1024 + 32 + scol], &kt[1][wid << 9]);
    GLOAD16(&vb[(long)srow * 1024 + s0 + scol], &vtt[0][wid << 9]);
    GLOAD16(&vb[(long)srow * 1024 + s0 + 32 + scol], &vtt[1][wid << 9]);
    __syncthreads();

    f32x4 sacc[2][4] = {};
    bf16x8 kf[4][2];
    #pragma unroll
    for (int ni = 0; ni < 4; ni++)
      #pragma unroll
      for (int ks = 0; ks < 2; ks++)
        kf[ni][ks] = *(const bf16x8*)&kt[ks][(colLane + ni * 16) * 32 + grp * 8];
    #pragma unroll
    for (int ks = 0; ks < 2; ks++)
      #pragma unroll
      for (int mi = 0; mi < 2; mi++)
        #pragma unroll
        for (int ni = 0; ni < 4; ni++)
          sacc[mi][ni] = __builtin_amdgcn_mfma_f32_16x16x32_bf16(qf[mi][ks], kf[ni][ks], sacc[mi][ni], 0, 0, 0);

    float mnew[2][4], sc[2][4], psum[2][4];
    #pragma unroll
    for (int mi = 0; mi < 2; mi++)
      #pragma unroll
      for (int r = 0; r < 4; r++) {
        float vx = fmaxf(fmaxf(sacc[mi][0][r], sacc[mi][1][r]),
                         fmaxf(sacc[mi][2][r], sacc[mi][3][r])) * 0.125f;
        #pragma unroll
        for (int o = 1; o < 16; o <<= 1) vx = fmaxf(vx, __shfl_xor(vx, o));
        float mn = fmaxf(m_[mi][r], vx);
        sc[mi][r] = __expf(m_[mi][r] - mn);
        m_[mi][r] = mn; mnew[mi][r] = mn;
        l_[mi][r] *= sc[mi][r];
        psum[mi][r] = 0.f;
      }
    #pragma unroll
    for (int mi = 0; mi < 2; mi++)
      #pragma unroll
      for (int ni = 0; ni < 4; ni++)
        #pragma unroll
        for (int r = 0; r < 4; r++)
          oacc[mi][ni][r] *= sc[mi][r];
    #pragma unroll
    for (int mi = 0; mi < 2; mi++)
      #pragma unroll
      for (int ni = 0; ni < 4; ni++)
        #pragma unroll
        for (int r = 0; r < 4; r++) {
          float p = __expf(sacc[mi][ni][r] * 0.125f - mnew[mi][r]);
          psum[mi][r] += p;
          pl[(mi * 16 + grp * 4 + r) * 72 + ni * 16 + colLane] = (bf16)p;
        }
    #pragma unroll
    for (int mi = 0; mi < 2; mi++)
      #pragma unroll
      for (int r = 0; r < 4; r++) {
        float ps = psum[mi][r];
        #pragma unroll
        for (int o = 1; o < 16; o <<= 1) ps += __shfl_xor(ps, o);
        l_[mi][r] += ps;
      }

    bf16x8 pa[2][2], vf[4][2];
    #pragma unroll
    for (int mi = 0; mi < 2; mi++)
      #pragma unroll
      for (int ks = 0; ks < 2; ks++)
        pa[mi][ks] = *(const bf16x8*)&pl[(colLane + mi * 16) * 72 + ks * 32 + grp * 8];
    #pragma unroll
    for (int ni = 0; ni < 4; ni++)
      #pragma unroll
      for (int ks = 0; ks < 2; ks++)
        vf[ni][ks] = *(const bf16x8*)&vtt[ks][(colLane + ni * 16) * 32 + grp * 8];
    #pragma unroll
    for (int ks = 0; ks < 2; ks++)
      #pragma unroll
      for (int mi = 0; mi < 2; mi++)
        #pragma unroll
        for (int ni = 0; ni < 4; ni++)
          oacc[mi][ni] = __builtin_amdgcn_mfma_f32_16x16x32_bf16(pa[mi][ks], vf[ni][ks], oacc[mi][ni], 0, 0, 0);
    __syncthreads();
  }

  #pragma unroll
  for (int mi = 0; mi < 2; mi++)
    #pragma unroll
    for (int r = 0; r < 4; r++) {
      float inv = 1.f / l_[mi][r];
      int t = qt * 128 + wid * 32 + mi * 16 + grp * 4 + r;
      long n = (long)t * 4 + b;
      #pragma unroll
      for (int ni = 0; ni < 4; ni++)
        ao[n * 1024 + h * 64 + ni * 16 + colLane] = (bf16)(oacc[mi][ni][r] * inv);
    }
}

// ---------------- residual add + LayerNorm (float4) ----------------
__global__ __launch_bounds__(256) void k_add_ln(const float* __restrict__ a, const float* __restrict__ b,
                                                const float* __restrict__ g, const float* __restrict__ be,
                                                float* __restrict__ out, bf16* __restrict__ outb) {
  long row = blockIdx.x;
  int tid = threadIdx.x;
  float4 va = ((const float4*)(a + row * 1024))[tid];
  float4 vb = ((const float4*)(b + row * 1024))[tid];
  float v[4] = {va.x + vb.x, va.y + vb.y, va.z + vb.z, va.w + vb.w};
  float s = v[0] + v[1] + v[2] + v[3];
  float sq = v[0] * v[0] + v[1] * v[1] + v[2] * v[2] + v[3] * v[3];
  #pragma unroll
  for (int o = 32; o; o >>= 1) { s += __shfl_xor(s, o); sq += __shfl_xor(sq, o); }
  __shared__ float r1[4], r2[4];
  int wid = tid >> 6;
  if ((tid & 63) == 0) { r1[wid] = s; r2[wid] = sq; }
  __syncthreads();
  s = r1[0] + r1[1] + r1[2] + r1[3];
  sq = r2[0] + r2[1] + r2[2] + r2[3];
  float mu = s * (1.f / 1024.f);
  float var = sq * (1.f / 1024.f) - mu * mu;
  float rstd = rsqrtf(var + 1e-5f);
  float4 vg = ((const float4*)g)[tid];
  float4 vbe = ((const float4*)be)[tid];
  float y0 = (v[0] - mu) * rstd * vg.x + vbe.x;
  float y1 = (v[1] - mu) * rstd * vg.y + vbe.y;
  float y2 = (v[2] - mu) * rstd * vg.z + vbe.z;
  float y3 = (v[3] - mu) * rstd * vg.w + vbe.w;
  ((float4*)(out + row * 1024))[tid] = make_float4(y0, y1, y2, y3);
  if (outb) {
    bf16x4 o = {(bf16)y0, (bf16)y1, (bf16)y2, (bf16)y3};
    ((bf16x4*)(outb + row * 1024))[tid] = o;
  }
}

// ---------------- residual add + LayerNorm + fused MoE gating ----------------
__global__ __launch_bounds__(256) void k_add_ln_gate(
    const float* __restrict__ a, const float* __restrict__ b,
    const float* __restrict__ g, const float* __restrict__ be,
    const float* __restrict__ wg, float* __restrict__ out,
    int* __restrict__ e1, int* __restrict__ e2,
    float* __restrict__ g1, float* __restrict__ g2) {
  long row = blockIdx.x;
  int tid = threadIdx.x;
  float4 va = ((const float4*)(a + row * 1024))[tid];
  float4 vb = ((const float4*)(b + row * 1024))[tid];
  float v[4] = {va.x + vb.x, va.y + vb.y, va.z + vb.z, va.w + vb.w};
  float s = v[0] + v[1] + v[2] + v[3];
  float sq = v[0] * v[0] + v[1] * v[1] + v[2] * v[2] + v[3] * v[3];
  #pragma unroll
  for (int o = 32; o; o >>= 1) { s += __shfl_xor(s, o); sq += __shfl_xor(sq, o); }
  __shared__ float r1[4], r2[4];
  __shared__ float gred[4][8];
  int wid = tid >> 6, lane = tid & 63;
  if (lane == 0) { r1[wid] = s; r2[wid] = sq; }
  __syncthreads();
  s = r1[0] + r1[1] + r1[2] + r1[3];
  sq = r2[0] + r2[1] + r2[2] + r2[3];
  float mu = s * (1.f / 1024.f);
  float var = sq * (1.f / 1024.f) - mu * mu;
  float rstd = rsqrtf(var + 1e-5f);
  float4 vg = ((const float4*)g)[tid];
  float4 vbe = ((const float4*)be)[tid];
  float y[4];
  y[0] = (v[0] - mu) * rstd * vg.x + vbe.x;
  y[1] = (v[1] - mu) * rstd * vg.y + vbe.y;
  y[2] = (v[2] - mu) * rstd * vg.z + vbe.z;
  y[3] = (v[3] - mu) * rstd * vg.w + vbe.w;
  ((float4*)(out + row * 1024))[tid] = make_float4(y[0], y[1], y[2], y[3]);
  // gating logits: acc[e] = sum_c y[c]*wg[c][e]; this thread's cols tid*4+j
  float acc[8] = {0.f, 0.f, 0.f, 0.f, 0.f, 0.f, 0.f, 0.f};
  const float* wr = wg + (long)tid * 32;
  #pragma unroll
  for (int j = 0; j < 4; j++) {
    float4 w0 = *(const float4*)(wr + j * 8);
    float4 w1 = *(const float4*)(wr + j * 8 + 4);
    acc[0] += y[j] * w0.x; acc[1] += y[j] * w0.y; acc[2] += y[j] * w0.z; acc[3] += y[j] * w0.w;
    acc[4] += y[j] * w1.x; acc[5] += y[j] * w1.y; acc[6] += y[j] * w1.z; acc[7] += y[j] * w1.w;
  }
  #pragma unroll
  for (int e = 0; e < 8; e++)
    #pragma unroll
    for (int o = 32; o; o >>= 1) acc[e] += __shfl_xor(acc[e], o);
  if (lane == 0) {
    #pragma unroll
    for (int e = 0; e < 8; e++) gred[wid][e] = acc[e];
  }
  __syncthreads();
  if (tid == 0) {
    float L[8];
    #pragma unroll
    for (int e = 0; e < 8; e++) L[e] = gred[0][e] + gred[1][e] + gred[2][e] + gred[3][e];
    int i1 = 0; float b1v = L[0];
    #pragma unroll
    for (int e = 1; e < 8; e++) if (L[e] > b1v) { b1v = L[e]; i1 = e; }
    int i2 = -1; float b2v = -INFINITY;
    #pragma unroll
    for (int e = 0; e < 8; e++) if (e != i1 && L[e] > b2v) { b2v = L[e]; i2 = e; }
    float den = 0.f;
    #pragma unroll
    for (int e = 0; e < 8; e++) den += __expf(L[e] - b1v);
    float gg1 = 1.f / den;
    float gg2 = __expf(b2v - b1v) / den;
    float dn = gg1 + gg2 + 1e-9f;
    e1[row] = i1; e2[row] = i2; g1[row] = gg1 / dn; g2[row] = gg2 / dn;
  }
}

// ---------------- capacity positions: one block per expert, ordered scan ----
__global__ __launch_bounds__(256) void k_positions(const int* __restrict__ e1, const int* __restrict__ e2,
                                                   const float* __restrict__ g1, const float* __restrict__ g2,
                                                   int* __restrict__ d1, int* __restrict__ d2,
                                                   float* __restrict__ s1, float* __restrict__ s2) {
  const int e = blockIdx.x;
  const int tid = threadIdx.x, lane = tid & 63, wid = tid >> 6;
  __shared__ int wsum[4];
  int f[16];
  int cnt = 0;
  #pragma unroll
  for (int i = 0; i < 16; i++) { f[i] = (e1[tid * 16 + i] == e) ? 1 : 0; cnt += f[i]; }
  int inc = cnt;
  #pragma unroll
  for (int o = 1; o < 64; o <<= 1) { int v = __shfl_up(inc, o); if (lane >= o) inc += v; }
  if (lane == 63) wsum[wid] = inc;
  __syncthreads();
  int base = inc - cnt;
  for (int w = 0; w < wid; w++) base += wsum[w];
  const int total1 = wsum[0] + wsum[1] + wsum[2] + wsum[3];
  int run = base;
  #pragma unroll
  for (int i = 0; i < 16; i++) {
    int n = tid * 16 + i;
    if (f[i]) {
      int p = run++;
      d1[n] = e * CAP_ + (p < CAP_ ? p : CAP_ - 1);
      s1[n] = (p < CAP_) ? g1[n] : 0.f;
    }
  }
  cnt = 0;
  #pragma unroll
  for (int i = 0; i < 16; i++) { f[i] = (e2[tid * 16 + i] == e) ? 1 : 0; cnt += f[i]; }
  inc = cnt;
  #pragma unroll
  for (int o = 1; o < 64; o <<= 1) { int v = __shfl_up(inc, o); if (lane >= o) inc += v; }
  __syncthreads();
  if (lane == 63) wsum[wid] = inc;
  __syncthreads();
  base = inc - cnt + total1;
  for (int w = 0; w < wid; w++) base += wsum[w];
  run = base;
  #pragma unroll
  for (int i = 0; i < 16; i++) {
    int n = tid * 16 + i;
    if (f[i]) {
      int p = run++;
      d2[n] = e * CAP_ + (p < CAP_ ? p : CAP_ - 1);
      s2[n] = (p < CAP_) ? g2[n] : 0.f;
    }
  }
}

// ---------------- scatter tokens into expert buffers ----------------
__global__ __launch_bounds__(256) void k_scatter(const float* __restrict__ x, const int* __restrict__ d1,
                                                 const int* __restrict__ d2, const float* __restrict__ s1,
                                                 const float* __restrict__ s2, bf16* __restrict__ buf) {
  int n = blockIdx.x;
  int tid = threadIdx.x;
  float4 v = ((const float4*)(x + (long)n * 1024))[tid];
  bf16x4 o = {(bf16)v.x, (bf16)v.y, (bf16)v.z, (bf16)v.w};
  if (s1[n] != 0.f) ((bf16x4*)(buf + (long)d1[n] * 1024))[tid] = o;
  if (s2[n] != 0.f) ((bf16x4*)(buf + (long)d2[n] * 1024))[tid] = o;
}

// ---------------- gather expert outputs (2 bf16 partials + b2) + LN3 --------
__global__ __launch_bounds__(256) void k_gather_ln(const float* __restrict__ x,
                                                   const bf16* __restrict__ p0, const bf16* __restrict__ p1,
                                                   const float* __restrict__ b2,
                                                   const int* __restrict__ d1, const int* __restrict__ d2,
                                                   const float* __restrict__ s1, const float* __restrict__ s2,
                                                   const float* __restrict__ g, const float* __restrict__ be,
                                                   float* __restrict__ out) {
  long n = blockIdx.x;
  int tid = threadIdx.x;
  float a1 = s1[n], a2 = s2[n];
  long i1 = (long)d1[n] * 1024, i2 = (long)d2[n] * 1024;
  long e1b = (long)(d1[n] >> 10) * 1024, e2b = (long)(d2[n] >> 10) * 1024;
  float4 vx = ((const float4*)(x + n * 1024))[tid];
  bf16x4 q10 = *(const bf16x4*)&p0[i1 + tid * 4];
  bf16x4 q11 = *(const bf16x4*)&p1[i1 + tid * 4];
  bf16x4 q20 = *(const bf16x4*)&p0[i2 + tid * 4];
  bf16x4 q21 = *(const bf16x4*)&p1[i2 + tid * 4];
  float4 vb1 = ((const float4*)(b2 + e1b))[tid];
  float4 vb2 = ((const float4*)(b2 + e2b))[tid];
  float v[4];
  float xs[4] = {vx.x, vx.y, vx.z, vx.w};
  float b1a[4] = {vb1.x, vb1.y, vb1.z, vb1.w};
  float b2a[4] = {vb2.x, vb2.y, vb2.z, vb2.w};
  float s = 0.f, sq = 0.f;
  #pragma unroll
  for (int i = 0; i < 4; i++) {
    float r1v = (float)q10[i] + (float)q11[i] + b1a[i];
    float r2v = (float)q20[i] + (float)q21[i] + b2a[i];
    float y = xs[i] + a1 * r1v + a2 * r2v;
    v[i] = y; s += y; sq += y * y;
  }
  #pragma unroll
  for (int o = 32; o; o >>= 1) { s += __shfl_xor(s, o); sq += __shfl_xor(sq, o); }
  __shared__ float r1[4], r2[4];
  int wid = tid >> 6;
  if ((tid & 63) == 0) { r1[wid] = s; r2[wid] = sq; }
  __syncthreads();
  s = r1[0] + r1[1] + r1[2] + r1[3];
  sq = r2[0] + r2[1] + r2[2] + r2[3];
  float mu = s * (1.f / 1024.f);
  float var = sq * (1.f / 1024.f) - mu * mu;
  float rstd = rsqrtf(var + 1e-5f);
  float4 vg = ((const float4*)g)[tid];
  float4 vbe = ((const float4*)be)[tid];
  float ga[4] = {vg.x, vg.y, vg.z, vg.w};
  float ba[4] = {vbe.x, vbe.y, vbe.z, vbe.w};
  float4 o;
  o.x = (v[0] - mu) * rstd * ga[0] + ba[0];
  o.y = (v[1] - mu) * rstd * ga[1] + ba[1];
  o.z = (v[2] - mu) * rstd * ga[2] + ba[2];
  o.w = (v[3] - mu) * rstd * ga[3] + ba[3];
  ((float4*)(out + n * 1024))[tid] = o;
}

// ---------------------------------------------------------------------------
extern "C" void kernel_launch(void* const* d_in, const int* in_sizes, int n_in,
                              void* d_out, int out_size, void* d_ws, size_t ws_size,
                              hipStream_t stream) {
  const float* tgt      = (const float*)d_in[0];
  const float* memory   = (const float*)d_in[1];
  const float* sa_in_w  = (const float*)d_in[2];
  const float* sa_in_b  = (const float*)d_in[3];
  const float* sa_out_w = (const float*)d_in[4];
  const float* sa_out_b = (const float*)d_in[5];
  const float* ca_in_w  = (const float*)d_in[6];
  const float* ca_in_b  = (const float*)d_in[7];
  const float* ca_out_w = (const float*)d_in[8];
  const float* ca_out_b = (const float*)d_in[9];
  const float* ln1_g    = (const float*)d_in[10];
  const float* ln1_b    = (const float*)d_in[11];
  const float* ln2_g    = (const float*)d_in[12];
  const float* ln2_b    = (const float*)d_in[13];
  const float* ln3_g    = (const float*)d_in[14];
  const float* ln3_b    = (const float*)d_in[15];
  const float* wg       = (const float*)d_in[16];
  const float* w1       = (const float*)d_in[17];
  const float* b1       = (const float*)d_in[18];
  const float* w2       = (const float*)d_in[19];
  const float* b2       = (const float*)d_in[20];

  char* ws = (char*)d_ws;
  auto B16 = [&](long o) { return (bf16*)(ws + o); };
  auto F32 = [&](long o) { return (float*)(ws + o); };
  auto I32 = [&](long o) { return (int*)(ws + o); };

  const dim3 blk256(256), blk512(512);

  // ---- phase 0: conversions to bf16 (single launch)
  k_cvt6<<<16384, blk256, 0, stream>>>(sa_in_w, sa_out_w, ca_in_w, ca_out_w, tgt, memory,
                                       B16(OFF_WSAIN), B16(OFF_WSAOUT), B16(OFF_WCAIN),
                                       B16(OFF_WCAOUT), B16(OFF_BTGT), B16(OFF_BMEM));

  // ---- phase 1: self-attention
  k_gemm8p<false, true, bf16><<<dim3(4, 16, 3), blk512, 0, stream>>>(
      B16(OFF_BTGT), B16(OFF_WSAIN), B16(OFF_QS), sa_in_b,
      1024, 1024, 1024, 1024, 1,
      0, 0, 1048576, 0, 4194304, 0, 1024);
  k_extract_vt<<<dim3(16, 64), blk256, 0, stream>>>(B16(OFF_VS), B16(OFF_VT));
  k_flash<<<dim3(8, 64), blk256, 0, stream>>>(B16(OFF_QS), B16(OFF_KS), B16(OFF_VT), B16(OFF_AO));
  k_gemm_nt<128, 64, 4, 1, false, false, float><<<dim3(16, 32, 1), blk256, 0, stream>>>(
      B16(OFF_AO), B16(OFF_WSAOUT), F32(OFF_PROJ), sa_out_b,
      1024, 1024, 1024, 1024, 1.f, 1, 0, 0, 0, 0, 0, 0, 0, 0);
  k_add_ln<<<4096, blk256, 0, stream>>>(tgt, F32(OFF_PROJ), ln1_g, ln1_b, F32(OFF_X1), B16(OFF_BTGT));

  // ---- phase 2: cross-attention (q/k/v in ONE launch: z=0 q, z=1 k, z=2 v)
  k_gemm_nt<128, 64, 4, 1, false, true, bf16><<<dim3(16, 32, 3), blk256, 0, stream>>>(
      B16(OFF_BTGT), B16(OFF_WCAIN), B16(OFF_QS), ca_in_b,
      1024, 1024, 1024, 1024, 1.f, 2,
      4194304, 4194304, 2097152, 1048576, 8388608, 4194304, 2048, 1024);
  k_extract_vt<<<dim3(16, 64), blk256, 0, stream>>>(B16(OFF_VS), B16(OFF_VT));
  k_flash<<<dim3(8, 64), blk256, 0, stream>>>(B16(OFF_QS), B16(OFF_KS), B16(OFF_VT), B16(OFF_AO));
  k_gemm_nt<128, 64, 4, 1, false, false, float><<<dim3(16, 32, 1), blk256, 0, stream>>>(
      B16(OFF_AO), B16(OFF_WCAOUT), F32(OFF_PROJ), ca_out_b,
      1024, 1024, 1024, 1024, 1.f, 1, 0, 0, 0, 0, 0, 0, 0, 0);
  // add+LN2 with fused gating
  k_add_ln_gate<<<4096, blk256, 0, stream>>>(F32(OFF_X1), F32(OFF_PROJ), ln2_g, ln2_b, wg,
                                             F32(OFF_X2), I32(OFF_E1), I32(OFF_E2),
                                             F32(OFF_G1), F32(OFF_G2));

  // ---- phase 3: MoE
  k_positions<<<8, blk256, 0, stream>>>(I32(OFF_E1), I32(OFF_E2), F32(OFF_G1), F32(OFF_G2),
                                        I32(OFF_D1), I32(OFF_D2), F32(OFF_S1), F32(OFF_S2));
  k_scatter<<<4096, blk256, 0, stream>>>(F32(OFF_X2), I32(OFF_D1), I32(OFF_D2),
                                         F32(OFF_S1), F32(OFF_S2), B16(OFF_QKV));
  k_transpose_f32_bf16<<<dim3(64, 16, 8), blk256, 0, stream>>>(w1, B16(OFF_SCORES), 1024, 4096);
  k_gemm8p<true, false, bf16><<<dim3(16, 4, 8), blk512, 0, stream>>>(
      B16(OFF_QKV), B16(OFF_SCORES), B16(OFF_H), b1,
      1024, 1024, 1024, 4096, 1,
      1048576, 0, 4194304, 0, 4194304, 0, 4096);
  k_transpose_f32_bf16<<<dim3(16, 64, 8), blk256, 0, stream>>>(w2, B16(OFF_SCORES), 4096, 1024);
  k_gemm8p<false, false, bf16><<<dim3(4, 4, 16), blk512, 0, stream>>>(
      B16(OFF_H), B16(OFF_SCORES), B16(OFF_PROJ), nullptr,
      2048, 4096, 4096, 1024, 2,
      4194304, 2048, 4194304, 2048, 1048576, (OFF_EO1 - OFF_PROJ) / 2, 0);
  k_gather_ln<<<4096, blk256, 0, stream>>>(F32(OFF_X2), B16(OFF_PROJ), B16(OFF_EO1), b2,
                                           I32(OFF_D1), I32(OFF_D2),
                                           F32(OFF_S1), F32(OFF_S2), ln3_g, ln3_b, (float*)d_out);

  (void)in_sizes; (void)n_in; (void)out_size; (void)ws_size;
}